// Round 8
// baseline (536.230 us; speedup 1.0000x reference)
//
#include <hip/hip_runtime.h>

// LSTM: B=8192, T=512, IN=8, H=64, OUT=1
// R8: dual-stream WGs. Each WG owns TWO independent 16-batch tiles (A,B);
//     grid 256 = 1 WG/CU, 4 waves/CU. Per round: step t of A, step t of B,
//     ONE barrier. B's MFMAs/ds_reads fill A's serial latency chain
//     (ds_read ~120cyc + MFMA chain + activation chain) that 2-wave TLP
//     couldn't fill in R5; barrier count per tile-step halves.
// R5: fused-rcp activation algebra (5 exp2 + 2 rcp per element), bias as
//     persistent MFMA C-operand, pk f32 math. 12 MFMA per wave-tile-step.
// R4: x staged via double-buffered LDS chunks of 16 steps (vmem drains only
//     once per 16 steps -- CHUNK=4 register variant regressed in R7).
// R2: activation scale folded into weights (-log2e i/f/o, +2log2e g).
// MFMA layouts (m89/m91/m120 verified):
//   A[m=lane&15][k=(lane>>4)*8+j], B[k=(lane>>4)*8+j][n=lane&15],
//   C/D: col=lane&15, row=(lane>>4)*4+reg.

typedef _Float16 f16_t;
typedef _Float16 half8 __attribute__((ext_vector_type(8)));
typedef __fp16 fp16x2 __attribute__((ext_vector_type(2)));
typedef float floatx2 __attribute__((ext_vector_type(2)));
typedef float floatx4 __attribute__((ext_vector_type(4)));

#define Bn 8192
#define Tn 512
#define INn 8
#define Hn 64
#define BT 16
#define NT 2          // batch tiles per WG (dual stream)
#define CHUNK 16
#define NCHUNK (Tn / CHUNK)
#define HSTRIDE 72    // f16; 36 words -> b128 h-reads 2-way aliased (free)
#define XTSTRIDE 136  // f16 per tt: 16 rows * 8 + 8 pad; 68 words skew

__device__ __forceinline__ floatx2 act_pair(float zi0, float zi1,
                                            float zf0, float zf1,
                                            float zg0, float zg1,
                                            float zo0, float zo1,
                                            floatx2& chat) {
  const floatx2 one  = {1.f, 1.f};
  const float  K2   = 2.8853900817779268f;  // 2*log2(e)
  const floatx2 K2v  = {K2, K2};
  const floatx2 mK2v = {-K2, -K2};
  const floatx2 clmp = {126.f, 126.f};
  floatx2 A = {__builtin_amdgcn_exp2f(zi0), __builtin_amdgcn_exp2f(zi1)};
  floatx2 G = {__builtin_amdgcn_exp2f(zg0), __builtin_amdgcn_exp2f(zg1)};
  floatx2 F = {__builtin_amdgcn_exp2f(zf0), __builtin_amdgcn_exp2f(zf1)};
  floatx2 O = {__builtin_amdgcn_exp2f(zo0), __builtin_amdgcn_exp2f(zo1)};
  floatx2 PA  = A + one;
  floatx2 PG  = G + one;
  floatx2 PF  = F + one;
  floatx2 PAG = PA * PG;
  floatx2 num = __builtin_elementwise_fma(G, K2v, mK2v) * PF;  // K(G-1)(1+F)
  floatx2 s   = __builtin_elementwise_fma(chat, PAG, num);
  floatx2 P3  = PF * PAG;
  floatx2 R   = {__builtin_amdgcn_rcpf(P3.x), __builtin_amdgcn_rcpf(P3.y)};
  chat = __builtin_elementwise_min(s * R, clmp);
  floatx2 C2 = {__builtin_amdgcn_exp2f(chat.x), __builtin_amdgcn_exp2f(chat.y)};
  floatx2 P4 = (O + one) * (C2 + one);
  floatx2 Rh = {__builtin_amdgcn_rcpf(P4.x), __builtin_amdgcn_rcpf(P4.y)};
  return (C2 - one) * Rh;  // h = o * tanh(c)
}

__device__ __forceinline__ void lstm_step(
    f16_t (&hb)[2][BT][HSTRIDE], const f16_t* __restrict__ xrow,
    int p, int n, int q, int u,
    const half8 (&bf)[4][3],
    const floatx4& bi, const floatx4& bfv, const floatx4& bg, const floatx4& bo,
    floatx2& chat01, floatx2& chat23)
{
  const int pn = p ^ 1;
  const half8 a0 = *(const half8*)&hb[p][n][q * 8];
  const half8 a1 = *(const half8*)&hb[p][n][32 + q * 8];
  const half8 a2 = *(const half8*)&xrow[n * 8];

  // bias regs as first-MFMA C operand (D != C): no per-step acc init
  floatx4 ai = __builtin_amdgcn_mfma_f32_16x16x32_f16(a0, bf[0][0], bi, 0, 0, 0);
  ai = __builtin_amdgcn_mfma_f32_16x16x32_f16(a1, bf[0][1], ai, 0, 0, 0);
  ai = __builtin_amdgcn_mfma_f32_16x16x32_f16(a2, bf[0][2], ai, 0, 0, 0);
  floatx4 af = __builtin_amdgcn_mfma_f32_16x16x32_f16(a0, bf[1][0], bfv, 0, 0, 0);
  af = __builtin_amdgcn_mfma_f32_16x16x32_f16(a1, bf[1][1], af, 0, 0, 0);
  af = __builtin_amdgcn_mfma_f32_16x16x32_f16(a2, bf[1][2], af, 0, 0, 0);
  floatx4 ag = __builtin_amdgcn_mfma_f32_16x16x32_f16(a0, bf[2][0], bg, 0, 0, 0);
  ag = __builtin_amdgcn_mfma_f32_16x16x32_f16(a1, bf[2][1], ag, 0, 0, 0);
  ag = __builtin_amdgcn_mfma_f32_16x16x32_f16(a2, bf[2][2], ag, 0, 0, 0);
  floatx4 ao = __builtin_amdgcn_mfma_f32_16x16x32_f16(a0, bf[3][0], bo, 0, 0, 0);
  ao = __builtin_amdgcn_mfma_f32_16x16x32_f16(a1, bf[3][1], ao, 0, 0, 0);
  ao = __builtin_amdgcn_mfma_f32_16x16x32_f16(a2, bf[3][2], ao, 0, 0, 0);

  const floatx2 h01 = act_pair(ai[0], ai[1], af[0], af[1],
                               ag[0], ag[1], ao[0], ao[1], chat01);
  const floatx2 h23 = act_pair(ai[2], ai[3], af[2], af[3],
                               ag[2], ag[3], ao[2], ao[3], chat23);

  hb[pn][q * 4 + 0][u] = (f16_t)h01.x;
  hb[pn][q * 4 + 1][u] = (f16_t)h01.y;
  hb[pn][q * 4 + 2][u] = (f16_t)h23.x;
  hb[pn][q * 4 + 3][u] = (f16_t)h23.y;
}

__global__ __launch_bounds__(256, 1)
void lstm_fused(const float* __restrict__ xg,
                const float* __restrict__ W_ih,
                const float* __restrict__ W_hh,
                const float* __restrict__ b_ih,
                const float* __restrict__ b_hh,
                const float* __restrict__ W_fc,
                const float* __restrict__ b_fc,
                float* __restrict__ out)
{
  __shared__ alignas(16) f16_t hbuf[NT][2][BT][HSTRIDE];
  __shared__ alignas(16) f16_t xlds[NT][2][CHUNK][XTSTRIDE];

  const int tid   = threadIdx.x;
  const int wv    = tid >> 6;     // wave 0..3 -> hidden units 16wv..16wv+15
  const int lane  = tid & 63;
  const int n     = lane & 15;    // A-row (batch) / B-col / D-col index
  const int q     = lane >> 4;    // quad
  const int bbase = blockIdx.x * (BT * NT);

  const float LOG2E = 1.4426950408889634f;

  // ---- B fragments (weights), pre-scaled, resident (shared by both tiles).
  // Gate g in {i,f,g,o}: column C = 64*g + 16*wv + n.
  // K layout: k in [0,64) = W_hh cols, [64,72) = W_ih cols, [72,96) = 0.
  half8 bf[4][3];
  #pragma unroll
  for (int g = 0; g < 4; ++g) {
    const float sc = (g == 2) ? (2.f * LOG2E) : (-LOG2E);
    const int C = g * 64 + wv * 16 + n;
    #pragma unroll
    for (int c = 0; c < 3; ++c) {
      half8 v;
      #pragma unroll
      for (int e = 0; e < 8; ++e) {
        const int k = c * 32 + q * 8 + e;
        float w = 0.f;
        if (k < Hn)            w = W_hh[C * Hn + k] * sc;
        else if (k < Hn + INn) w = W_ih[C * INn + (k - Hn)] * sc;
        v[e] = (f16_t)w;
      }
      bf[g][c] = v;
    }
  }

  // ---- scaled biases -> persistent MFMA C-operand registers
  const int u = wv * 16 + n;  // this lane's hidden unit (acc column)
  const float pb_i = -(b_ih[u]       + b_hh[u])       * LOG2E;
  const float pb_f = -(b_ih[64 + u]  + b_hh[64 + u])  * LOG2E;
  const float pb_g =  (b_ih[128 + u] + b_hh[128 + u]) * (2.f * LOG2E);
  const float pb_o = -(b_ih[192 + u] + b_hh[192 + u]) * LOG2E;
  const floatx4 bi  = {pb_i, pb_i, pb_i, pb_i};
  const floatx4 bfv = {pb_f, pb_f, pb_f, pb_f};
  const floatx4 bg  = {pb_g, pb_g, pb_g, pb_g};
  const floatx4 bo  = {pb_o, pb_o, pb_o, pb_o};

  // ---- LDS init: h0 = 0 (both tiles, both parities)
  for (int i = tid; i < NT * 2 * BT * HSTRIDE; i += 256)
    ((f16_t*)hbuf)[i] = (f16_t)0.f;

  // ---- x staging: lane -> (row, tt); two float4 per thread per tile
  const int row_s = tid >> 4;   // 0..15 batch row within tile
  const int tt_s  = tid & 15;   // 0..15 timestep within chunk
  const float* xpsA = xg + ((size_t)(bbase + row_s) * Tn + tt_s) * INn;
  const float* xpsB = xpsA + (size_t)BT * Tn * INn;

  // preload chunk 0 for both tiles
  float4 paA = *(const float4*)(xpsA);
  float4 pbA = *(const float4*)(xpsA + 4);
  float4 paB = *(const float4*)(xpsB);
  float4 pbB = *(const float4*)(xpsB + 4);

  floatx2 chatA01 = {0.f, 0.f}, chatA23 = {0.f, 0.f};
  floatx2 chatB01 = {0.f, 0.f}, chatB23 = {0.f, 0.f};

  for (int ch = 0; ch < NCHUNK; ++ch) {
    // ---- write staged chunk to LDS (f16), both tiles
    {
      union { half8 v; fp16x2 h2[4]; } P;
      P.h2[0] = __builtin_amdgcn_cvt_pkrtz(paA.x, paA.y);
      P.h2[1] = __builtin_amdgcn_cvt_pkrtz(paA.z, paA.w);
      P.h2[2] = __builtin_amdgcn_cvt_pkrtz(pbA.x, pbA.y);
      P.h2[3] = __builtin_amdgcn_cvt_pkrtz(pbA.z, pbA.w);
      *(half8*)&xlds[0][ch & 1][tt_s][row_s * 8] = P.v;
      P.h2[0] = __builtin_amdgcn_cvt_pkrtz(paB.x, paB.y);
      P.h2[1] = __builtin_amdgcn_cvt_pkrtz(paB.z, paB.w);
      P.h2[2] = __builtin_amdgcn_cvt_pkrtz(pbB.x, pbB.y);
      P.h2[3] = __builtin_amdgcn_cvt_pkrtz(pbB.z, pbB.w);
      *(half8*)&xlds[1][ch & 1][tt_s][row_s * 8] = P.v;
    }
    __syncthreads();  // xlds chunk + (first iter) hbuf zero visible

    // ---- prefetch next chunk (uniform wrap; drained at most once/16 steps)
    const int chn = (ch + 1 < NCHUNK) ? (ch + 1) : 0;
    paA = *(const float4*)(xpsA + (size_t)chn * CHUNK * INn);
    pbA = *(const float4*)(xpsA + (size_t)chn * CHUNK * INn + 4);
    paB = *(const float4*)(xpsB + (size_t)chn * CHUNK * INn);
    pbB = *(const float4*)(xpsB + (size_t)chn * CHUNK * INn + 4);

    #pragma unroll 4
    for (int tt = 0; tt < CHUNK; ++tt) {
      const int p = tt & 1;   // CHUNK even -> global parity == tt&1
      lstm_step(hbuf[0], &xlds[0][ch & 1][tt][0], p, n, q, u,
                bf, bi, bfv, bg, bo, chatA01, chatA23);
      lstm_step(hbuf[1], &xlds[1][ch & 1][tt][0], p, n, q, u,
                bf, bi, bfv, bg, bo, chatB01, chatB23);
      __syncthreads();  // one barrier per round (2 tile-steps)
    }
  }

  // ---- epilogue: out[b] = h_T[b,:] . W_fc + b_fc ; wave wv handles tile wv
  if (wv < NT) {
    const int b = lane & 15;
    const int part = lane >> 4;
    float acc = 0.f;
    #pragma unroll
    for (int k = 0; k < 16; ++k) {
      const int uu = part * 16 + k;
      acc = __builtin_fmaf((float)hbuf[wv][0][b][uu], W_fc[uu], acc);
    }
    acc += __shfl_down(acc, 32);
    acc += __shfl_down(acc, 16);
    if (lane < 16) out[bbase + wv * BT + b] = acc + b_fc[0];
  }
}

extern "C" void kernel_launch(void* const* d_in, const int* in_sizes, int n_in,
                              void* d_out, int out_size, void* d_ws, size_t ws_size,
                              hipStream_t stream) {
  const float* x    = (const float*)d_in[0];
  const float* W_ih = (const float*)d_in[1];
  const float* W_hh = (const float*)d_in[2];
  const float* b_ih = (const float*)d_in[3];
  const float* b_hh = (const float*)d_in[4];
  const float* W_fc = (const float*)d_in[5];
  const float* b_fc = (const float*)d_in[6];
  float* out = (float*)d_out;
  dim3 grid(Bn / (BT * NT)), block(256);
  hipLaunchKernelGGL(lstm_fused, grid, block, 0, stream,
                     x, W_ih, W_hh, b_ih, b_hh, W_fc, b_fc, out);
}